// Round 1
// baseline (147.132 us; speedup 1.0000x reference)
//
#include <hip/hip_runtime.h>

// LeNet-5 forward, fully fused. ROUND 14: TWO IMAGES PER BLOCK (128 thr, 2 waves).
//
// Rationale (rocprof round 13): latency-bound — HBM 1.2% peak, MfmaUtil 33%,
// VALUBusy 31%, occupancy 36%. Per-block L2 weight traffic was ~356 KB per
// 3 KB image (conv2 weights read by BOTH waves), ~17 TB/s sustained from L2
// (~50% of ceiling) with latencies distance-1 prefetch can't hide.
//
// Round-14 restructure:
//  * block = 2 images. conv1: nt-split (6 nt/wave in 2 groups of 3), each
//    weight fragment feeds 4 m-tiles (both images) -> 54 KB/img (was 108).
//  * conv2/conv3/fc: wave w owns image w. conv2: 7 m-tiles/wave, one weight
//    stream per image (82 KB/img, was 164). conv3: 3 m-tiles/wave (42/img,
//    was 84). MFMA density per weight load doubles (14 MFMA/it in conv2).
//  * barriers 6 -> 3: after the post-conv2 barrier, waves are fully
//    independent (own h2/h3/fc region), relying on per-wave in-order LDS.
//
// Layouts (unchanged math from round 7):
//   conv1 as GEMM (row-only im2col), banded weights K=288, N=192.
//   h1: bf16 19x248 ([x*12+c], pads zeroed), per image       (2x 4712 elems)
//   h2: bf16 10x248 ([x*20+c], pads zeroed), per image       (2x 2480 elems)
//   h3: fp32 720, per image, inside own h2 region.
//   all K-padding baked into pre-packed weights (zeros).

typedef short s16x4 __attribute__((ext_vector_type(4)));
typedef short s16x8 __attribute__((ext_vector_type(8)));
typedef float f32x4 __attribute__((ext_vector_type(4)));

#define ROW1 248
#define ROW2 248
#define H1SZ 4712           // 19*248
#define H2SZ 2480           // 10*248
#define XOFF 9424           // xbf elem offset (= 2*H1SZ)
#define SM_BYTES 22048      // (2*4712 + 2*800) ushorts

static __device__ __forceinline__ unsigned short f2bf(float f) {
    union { float f; unsigned int u; } v; v.f = f;
    unsigned int u = v.u;
    unsigned int r = (u + 0x7fffu + ((u >> 16) & 1u)) >> 16;   // RNE
    return (unsigned short)r;
}

static __device__ __forceinline__ s16x8 cat8(s16x4 lo, s16x4 hi) {
    return __builtin_shufflevector(lo, hi, 0, 1, 2, 3, 4, 5, 6, 7);
}

// ---- weight prep (unchanged) ----------------------------------------------
// wbuf ushort: [0,40960) conv2 B-frags, [40960,61440) conv3 B-frags,
//              [61440,116736) conv1 banded B-frags (wband).
// All use the 16x16x32 B-frag convention: n = nt*16 + (lane&15),
// k = kc*32 + ((lane>>4)&3)*8 + t.
__global__ __launch_bounds__(256) void wprep_k(const float* __restrict__ w1,
                                               const float* __restrict__ w2,
                                               const float* __restrict__ w3,
                                               unsigned short* __restrict__ wbuf) {
    int e = blockIdx.x * 256 + threadIdx.x;
    if (e < 40960) {                       // conv2: j=k/12, c=k%12
        int t = e & 7, lane = (e >> 3) & 63, nt = (e >> 9) & 1;
        int ck = (e >> 10) & 3, i = e >> 12;
        int k = ck * 32 + ((lane >> 4) & 3) * 8 + t;
        int o = nt * 16 + (lane & 15);
        int j = k / 12, c = k % 12;
        float val = (j < 10 && c < 10 && o < 20) ? w2[o * 1000 + c * 100 + i * 10 + j] : 0.f;
        wbuf[e] = f2bf(val);
    } else if (e < 61440) {                // conv3: j=k/20, c=k%20
        int e2 = e - 40960;
        int t = e2 & 7, lane = (e2 >> 3) & 63, nt = (e2 >> 9) & 1;
        int ck = (e2 >> 10) & 3, i = e2 >> 12;
        int k = ck * 32 + ((lane >> 4) & 3) * 8 + t;
        int o = nt * 16 + (lane & 15);
        int j = k / 20, c = k % 20;
        float val = (j < 5 && o < 20) ? w3[o * 500 + c * 25 + i * 5 + j] : 0.f;
        wbuf[e] = f2bf(val);
    } else {                               // conv1 band: [nt(12)][kc(9)][lane][t]
        int e2 = e - 61440;                // < 55296
        int t = e2 & 7, lane = (e2 >> 3) & 63;
        int kc = (e2 >> 9) % 9, nt = (e2 >> 9) / 9;
        int n = nt * 16 + (lane & 15);
        int k = kc * 32 + ((lane >> 4) & 3) * 8 + t;
        float val = 0.f;
        if (n < 190 && k < 280) {
            int ox = n / 10, o = n - ox * 10;
            int i = k / 28, xc = k - i * 28;
            int j = xc - ox;
            if (j >= 0 && j < 10) val = w1[o * 100 + i * 10 + j];
        }
        wbuf[61440 + e2] = f2bf(val);
    }
}

// --------------------------- the fused kernel ------------------------------
__global__ __launch_bounds__(128, 4) void fused_k(const float* __restrict__ x,
                                                  const float* __restrict__ b1,
                                                  const unsigned short* __restrict__ wbuf2,
                                                  const unsigned short* __restrict__ wbuf3,
                                                  const unsigned short* __restrict__ wband,
                                                  const float* __restrict__ b2,
                                                  const float* __restrict__ b3,
                                                  const float* __restrict__ wf,
                                                  const float* __restrict__ bf,
                                                  float* __restrict__ out) {
    __shared__ __align__(16) unsigned char smem[SM_BYTES];
    unsigned short* sm16 = (unsigned short*)smem;
    unsigned short* h1  = sm16;                 // [2][4712]
    unsigned short* xbf = sm16 + XOFF;          // [2][800]

    const int tid = threadIdx.x;
    const int wave = tid >> 6, lane = tid & 63;
    const int b0 = blockIdx.x * 2;
    const int quad = lane >> 4, lm = lane & 15;

    // ---- phase 1: stage both images as bf16; zero tails + h1 pads ---------
    {
        const float4* src = (const float4*)(x + (size_t)b0 * 784);
        for (int k = tid; k < 392; k += 128) {
            float4 v = src[k];
            int img = (k >= 196);
            int idx = k - img * 196;
            s16x4 p = { (short)f2bf(v.x), (short)f2bf(v.y),
                        (short)f2bf(v.z), (short)f2bf(v.w) };
            *(s16x4*)(xbf + img * 800 + idx * 4) = p;
        }
        if (tid < 32) xbf[(tid >> 4) * 800 + 784 + (tid & 15)] = 0;
        for (int e = tid; e < 190; e += 128) {         // row pads [228,248) x 19 x 2
            int img = (e >= 95); int e2 = e - img * 95;
            int row = e2 / 5, seg = e2 - row * 5;
            *(s16x4*)(h1 + img * H1SZ + row * ROW1 + 228 + seg * 4) = (s16x4){0, 0, 0, 0};
        }
        for (int e = tid; e < 722; e += 128) {         // c-pads (oy,ox,[10,12)) x 2
            int img = (e >= 361); int e2 = e - img * 361;
            int oy = e2 / 19, ox = e2 - oy * 19;
            *(unsigned int*)(h1 + img * H1SZ + oy * ROW1 + ox * 12 + 10) = 0u;
        }
    }
    __syncthreads();

    // ---- phase 2: conv1 MFMA  M=64(2x19), N=192(190), K=288(280) ----------
    // wave w -> nt = w*6 .. w*6+5, split in 2 groups of 3 (register pressure).
    // Each weight fragment feeds 4 m-tiles: (img0,h0),(img0,h1),(img1,h0),(img1,h1).
    {
        int ab[4];
        {
            int r0 = lm;
            int r1 = lm + 16; if (r1 > 18) r1 = 18;    // clamp pad rows
            ab[0] = r0 * 28 + quad * 8;
            ab[1] = r1 * 28 + quad * 8;
            ab[2] = 800 + r0 * 28 + quad * 8;
            ab[3] = 800 + r1 * 28 + quad * 8;
        }
        const unsigned short* wb = wband + lane * 8;
#pragma unroll
        for (int g = 0; g < 2; ++g) {
            f32x4 acc1[3][4] = {};
#pragma unroll
            for (int kc = 0; kc < 9; ++kc) {
                s16x8 a[4];
#pragma unroll
                for (int mt = 0; mt < 4; ++mt)
                    a[mt] = cat8(*(const s16x4*)(xbf + ab[mt] + kc * 32),
                                 *(const s16x4*)(xbf + ab[mt] + kc * 32 + 4));
#pragma unroll
                for (int q = 0; q < 3; ++q) {
                    int nt = wave * 6 + g * 3 + q;
                    s16x8 bw = *(const s16x8*)(wb + (nt * 9 + kc) * 512);
#pragma unroll
                    for (int mt = 0; mt < 4; ++mt)
                        acc1[q][mt] = __builtin_amdgcn_mfma_f32_16x16x32_bf16(a[mt], bw, acc1[q][mt], 0, 0, 0);
                }
            }
#pragma unroll
            for (int q = 0; q < 3; ++q) {
                int n = (wave * 6 + g * 3 + q) * 16 + lm;
                if (n < 190) {
                    int ox = n / 10, o = n - ox * 10;
                    float bias = b1[o];
#pragma unroll
                    for (int mt = 0; mt < 4; ++mt) {
                        int img = mt >> 1, half = mt & 1;
#pragma unroll
                        for (int r = 0; r < 4; ++r) {
                            int oy = half * 16 + quad * 4 + r;
                            if (oy < 19)
                                h1[img * H1SZ + oy * ROW1 + ox * 12 + o] =
                                    f2bf(fmaxf(acc1[q][mt][r] + bias, 0.f));
                        }
                    }
                }
            }
        }
    }
    __syncthreads();

    // ---- phase 3: conv2 MFMA  M=112(100), N=32(20), K=1280(1000) ----------
    // wave w -> image w, all 7 m-tiles. 40 unrolled steps, distance-1 weight
    // prefetch; A-frags loaded in-body (full unroll lets compiler pipeline).
    const unsigned short* h1w = h1 + wave * H1SZ;
    int abase[7];
#pragma unroll
    for (int mt = 0; mt < 7; ++mt) {
        int m = mt * 16 + lm; if (m > 99) m = 99;
        int y = m / 10, xx = m - 10 * y;
        abase[mt] = y * ROW1 + xx * 12 + quad * 8;
    }
    f32x4 acc[7][2] = {};
    {
        const unsigned short* wptr = wbuf2 + lane * 8;
        s16x8 wc0 = *(const s16x8*)(wptr);
        s16x8 wc1 = *(const s16x8*)(wptr + 512);
#pragma unroll
        for (int it = 0; it < 40; ++it) {
            s16x8 wn0 = *(const s16x8*)(wptr + (it + 1) * 1024);   // tail->conv3 region
            s16x8 wn1 = *(const s16x8*)(wptr + (it + 1) * 1024 + 512);
            const unsigned short* sb = h1w + (it >> 2) * ROW1 + (it & 3) * 32;
            s16x8 af[7];
#pragma unroll
            for (int mt = 0; mt < 7; ++mt)
                af[mt] = cat8(*(const s16x4*)(sb + abase[mt]),
                              *(const s16x4*)(sb + abase[mt] + 4));
#pragma unroll
            for (int mt = 0; mt < 7; ++mt) {
                acc[mt][0] = __builtin_amdgcn_mfma_f32_16x16x32_bf16(af[mt], wc0, acc[mt][0], 0, 0, 0);
                acc[mt][1] = __builtin_amdgcn_mfma_f32_16x16x32_bf16(af[mt], wc1, acc[mt][1], 0, 0, 0);
            }
            wc0 = wn0; wc1 = wn1;
        }
    }
    __syncthreads();   // h1 (both images) fully consumed; region becomes h2
    // ===== from here on the waves are fully independent: wave w only touches
    // ===== its own h2/h3 region [w*4960, w*4960+4960) bytes. No more barriers.

    // ---- phase 4: zero h2 row-pads + scatter conv2 -> h2w ([x*20+c]) ------
    unsigned short* h2w = sm16 + wave * H2SZ;
    for (int e = lane; e < 120; e += 64) {             // pads [200,248) x 10
        int row = e / 12, seg = e - row * 12;
        *(s16x4*)(h2w + row * ROW2 + 200 + seg * 4) = (s16x4){0, 0, 0, 0};
    }
#pragma unroll
    for (int mt = 0; mt < 7; ++mt) {
#pragma unroll
        for (int nt = 0; nt < 2; ++nt) {
            int o = nt * 16 + lm;
            if (o < 20) {
                float bias = b2[o];
#pragma unroll
                for (int r = 0; r < 4; ++r) {
                    int pos = mt * 16 + quad * 4 + r;
                    if (pos < 100) {
                        int y2 = pos / 10, x2 = pos - 10 * y2;
                        h2w[y2 * ROW2 + x2 * 20 + o] =
                            f2bf(fmaxf(acc[mt][nt][r] + bias, 0.f));
                    }
                }
            }
        }
    }

    // ---- phase 5: conv3 MFMA  M=48(36), N=32(20), K=640(500) --------------
    // wave w -> image w, 3 m-tiles. 20 unrolled steps, weight prefetch.
    int abase3[3];
#pragma unroll
    for (int mt = 0; mt < 3; ++mt) {
        int m = mt * 16 + lm; if (m > 35) m = 35;
        int oy = m / 6, ox = m - 6 * oy;
        abase3[mt] = oy * ROW2 + ox * 20 + quad * 8;
    }
    f32x4 acc3[3][2] = {};
    {
        const unsigned short* wptr = wbuf3 + lane * 8;
        s16x8 wc0 = *(const s16x8*)(wptr);
        s16x8 wc1 = *(const s16x8*)(wptr + 512);
#pragma unroll
        for (int it = 0; it < 20; ++it) {
            s16x8 wn0 = *(const s16x8*)(wptr + (it + 1) * 1024);   // tail -> wband
            s16x8 wn1 = *(const s16x8*)(wptr + (it + 1) * 1024 + 512);
            const unsigned short* sb = h2w + (it >> 2) * ROW2 + (it & 3) * 32;
            s16x8 af[3];
#pragma unroll
            for (int mt = 0; mt < 3; ++mt)
                af[mt] = cat8(*(const s16x4*)(sb + abase3[mt]),
                              *(const s16x4*)(sb + abase3[mt] + 4));
#pragma unroll
            for (int mt = 0; mt < 3; ++mt) {
                acc3[mt][0] = __builtin_amdgcn_mfma_f32_16x16x32_bf16(af[mt], wc0, acc3[mt][0], 0, 0, 0);
                acc3[mt][1] = __builtin_amdgcn_mfma_f32_16x16x32_bf16(af[mt], wc1, acc3[mt][1], 0, 0, 0);
            }
            wc0 = wn0; wc1 = wn1;
        }
    }

    // ---- phase 6: conv3 epilogue -> linear h3w[o*36+pos] (fp32, relu) -----
    // h3w lives inside this wave's own h2 region (2880 B <= 4960 B); per-wave
    // LDS ops are in-order, so no barrier needed.
    float* h3w = (float*)(smem + wave * (H2SZ * 2));
#pragma unroll
    for (int mt = 0; mt < 3; ++mt) {
#pragma unroll
        for (int nt = 0; nt < 2; ++nt) {
            int o = nt * 16 + lm;
            if (o < 20) {
                float b3v = b3[o];
#pragma unroll
                for (int r = 0; r < 4; ++r) {
                    int pos = mt * 16 + quad * 4 + r;
                    if (pos < 36)
                        h3w[o * 36 + pos] = fmaxf(acc3[mt][nt][r] + b3v, 0.f);
                }
            }
        }
    }

    // ---- phase 7: fc — coalesced global wf; single-wave reduce ------------
    float part[10];
#pragma unroll
    for (int n = 0; n < 10; ++n) part[n] = 0.f;
#pragma unroll 1
    for (int s = 0; s < 12; ++s) {
        int k = s * 64 + lane;
        if (k < 720) {
            float v = h3w[k];
#pragma unroll
            for (int n = 0; n < 10; ++n)
                part[n] = fmaf(v, wf[n * 720 + k], part[n]);
        }
    }
#pragma unroll
    for (int n = 0; n < 10; ++n) {
#pragma unroll
        for (int off = 32; off >= 1; off >>= 1)
            part[n] += __shfl_xor(part[n], off, 64);
    }
    if (lane == 0) {
        float* dst = out + (size_t)(b0 + wave) * 10;
#pragma unroll
        for (int n = 0; n < 10; ++n) dst[n] = part[n] + bf[n];
    }
}

extern "C" void kernel_launch(void* const* d_in, const int* in_sizes, int n_in,
                              void* d_out, int out_size, void* d_ws, size_t ws_size,
                              hipStream_t stream) {
    (void)n_in; (void)out_size; (void)ws_size;
    const float* x  = (const float*)d_in[0];
    const float* w1 = (const float*)d_in[1];
    const float* b1 = (const float*)d_in[2];
    const float* w2 = (const float*)d_in[3];
    const float* b2 = (const float*)d_in[4];
    const float* w3 = (const float*)d_in[5];
    const float* b3 = (const float*)d_in[6];
    const float* wf = (const float*)d_in[7];
    const float* bf = (const float*)d_in[8];
    float* out = (float*)d_out;

    const int B = in_sizes[0] / 784;                   // 4096

    unsigned short* wbuf = (unsigned short*)d_ws;      // 116736 bf16 = 228 KB

    wprep_k<<<456, 256, 0, stream>>>(w1, w2, w3, wbuf);
    fused_k<<<B / 2, 128, 0, stream>>>(x, b1, wbuf, wbuf + 40960, wbuf + 61440,
                                       b2, b3, wf, bf, out);
}

// Round 2
// 145.717 us; speedup vs baseline: 1.0097x; 1.0097x over previous
//
#include <hip/hip_runtime.h>

// LeNet-5 forward, fully fused. ROUND 15: 8-RESIDENT, ZERO-BARRIER.
//
// Rocprof round 14: dur flat vs r13 despite halved L2 traffic; occupancy 26%
// == (7+1)/2 blocks predicted by LDS residency: 22528 B/block -> 7 blocks/CU
// resident but grid gives 8/CU -> every CU runs 7 blocks then 1 straggler;
// half the kernel runs at ~12% utilization. L2 BW is NOT the limiter.
//
// Round-15 restructure:
//  * LDS 22528 -> 20464 B so ALL 8 blocks/CU are co-resident (160K/8=20480):
//     - ROW1 248 -> 228 (no row pads; over-reads hit weight-zero K, finite)
//     - xbf exactly 784 elems (kc=8/quad=3 frag is weight-zero -> zero-subst)
//     - h2 (10x248) and h3 (720 f32) OVERLAY the wave's own h1 region
//  * ZERO __syncthreads: wave w owns image w end-to-end. Per-wave in-order
//    LDS makes the h1->h2->h3 overlay safe. conv1 band read per wave
//    (108 KB/img, 2x r14) is the price; L2 has headroom (was ~25% ceiling).
//  * s_setprio(1) around conv2/conv3 MFMA bursts (waves now phase-diverse).
//
// Layouts:
//   conv1 as GEMM (row-only im2col), banded weights K=288, N=192.
//   h1: bf16 19x228 ([x*12+c], c-pads zeroed), per image  (4332 elems)
//   xbf: bf16 784, per image (no tail)
//   h2: bf16 10x248 ([x*20+c]) overlaid on own h1; pads read old-finite data
//   h3: fp32 720 overlaid on own h1.

typedef short s16x4 __attribute__((ext_vector_type(4)));
typedef short s16x8 __attribute__((ext_vector_type(8)));
typedef float f32x4 __attribute__((ext_vector_type(4)));

#define ROW1 228
#define ROW2 248
#define H1SZ 4332           // 19*228
#define IMSZ 5116           // H1SZ + 784 (xbf)
#define SM_ELEMS 10232      // 2*IMSZ
#define XBOFF 4332

static __device__ __forceinline__ unsigned short f2bf(float f) {
    union { float f; unsigned int u; } v; v.f = f;
    unsigned int u = v.u;
    unsigned int r = (u + 0x7fffu + ((u >> 16) & 1u)) >> 16;   // RNE
    return (unsigned short)r;
}

static __device__ __forceinline__ s16x8 cat8(s16x4 lo, s16x4 hi) {
    return __builtin_shufflevector(lo, hi, 0, 1, 2, 3, 4, 5, 6, 7);
}

// ---- weight prep (unchanged layouts) --------------------------------------
// wbuf ushort: [0,40960) conv2 B-frags, [40960,61440) conv3 B-frags,
//              [61440,116736) conv1 banded B-frags (wband).
// 16x16x32 B-frag convention: n = nt*16 + (lane&15), k = kc*32 + quad*8 + t.
__global__ __launch_bounds__(256) void wprep_k(const float* __restrict__ w1,
                                               const float* __restrict__ w2,
                                               const float* __restrict__ w3,
                                               unsigned short* __restrict__ wbuf) {
    int e = blockIdx.x * 256 + threadIdx.x;
    if (e < 40960) {                       // conv2: j=k/12, c=k%12
        int t = e & 7, lane = (e >> 3) & 63, nt = (e >> 9) & 1;
        int ck = (e >> 10) & 3, i = e >> 12;
        int k = ck * 32 + ((lane >> 4) & 3) * 8 + t;
        int o = nt * 16 + (lane & 15);
        int j = k / 12, c = k % 12;
        float val = (j < 10 && c < 10 && o < 20) ? w2[o * 1000 + c * 100 + i * 10 + j] : 0.f;
        wbuf[e] = f2bf(val);
    } else if (e < 61440) {                // conv3: j=k/20, c=k%20
        int e2 = e - 40960;
        int t = e2 & 7, lane = (e2 >> 3) & 63, nt = (e2 >> 9) & 1;
        int ck = (e2 >> 10) & 3, i = e2 >> 12;
        int k = ck * 32 + ((lane >> 4) & 3) * 8 + t;
        int o = nt * 16 + (lane & 15);
        int j = k / 20, c = k % 20;
        float val = (j < 5 && o < 20) ? w3[o * 500 + c * 25 + i * 5 + j] : 0.f;
        wbuf[e] = f2bf(val);
    } else {                               // conv1 band: [nt(12)][kc(9)][lane][t]
        int e2 = e - 61440;                // < 55296
        int t = e2 & 7, lane = (e2 >> 3) & 63;
        int kc = (e2 >> 9) % 9, nt = (e2 >> 9) / 9;
        int n = nt * 16 + (lane & 15);
        int k = kc * 32 + ((lane >> 4) & 3) * 8 + t;
        float val = 0.f;
        if (n < 190 && k < 280) {
            int ox = n / 10, o = n - ox * 10;
            int i = k / 28, xc = k - i * 28;
            int j = xc - ox;
            if (j >= 0 && j < 10) val = w1[o * 100 + i * 10 + j];
        }
        wbuf[61440 + e2] = f2bf(val);
    }
}

// --------------------------- the fused kernel ------------------------------
__global__ __launch_bounds__(128, 4) void fused_k(const float* __restrict__ x,
                                                  const float* __restrict__ b1,
                                                  const unsigned short* __restrict__ wbuf2,
                                                  const unsigned short* __restrict__ wbuf3,
                                                  const unsigned short* __restrict__ wband,
                                                  const float* __restrict__ b2,
                                                  const float* __restrict__ b3,
                                                  const float* __restrict__ wf,
                                                  const float* __restrict__ bf,
                                                  float* __restrict__ out) {
    __shared__ __align__(16) unsigned short sm16[SM_ELEMS];

    const int tid = threadIdx.x;
    const int wave = tid >> 6, lane = tid & 63;
    const int img = blockIdx.x * 2 + wave;             // this wave's image
    const int quad = lane >> 4, lm = lane & 15;

    unsigned short* h1w  = sm16 + wave * IMSZ;         // [0, 4332) own region
    unsigned short* xbfw = h1w + XBOFF;                // [4332, 5116)

    // ---- phase 1 (per-wave): stage own image bf16 + zero h1 c-pads --------
    {
        const float4* src = (const float4*)(x + (size_t)img * 784);
        for (int k = lane; k < 196; k += 64) {
            float4 v = src[k];
            s16x4 p = { (short)f2bf(v.x), (short)f2bf(v.y),
                        (short)f2bf(v.z), (short)f2bf(v.w) };
            *(s16x4*)(xbfw + k * 4) = p;
        }
        for (int e = lane; e < 361; e += 64) {         // c-pads (oy,ox,[10,12))
            int oy = e / 19, ox = e - oy * 19;
            *(unsigned int*)(h1w + oy * ROW1 + ox * 12 + 10) = 0u;
        }
    }
    // no barrier: this wave wrote everything it will read.

    // ---- phase 2 (per-wave): conv1 MFMA  M=32(19), N=192(190), K=288(280) -
    // All 12 nt tiles for own image, in 2 register passes of 6.
    {
        int ab0 = lm * 28 + quad * 8;
        int r1 = lm + 16; if (r1 > 18) r1 = 18;        // clamp pad rows
        int ab1 = r1 * 28 + quad * 8;
        const unsigned short* wb = wband + lane * 8;
#pragma unroll
        for (int g = 0; g < 2; ++g) {
            f32x4 acc1[6][2] = {};
#pragma unroll
            for (int kc = 0; kc < 9; ++kc) {
                s16x8 a0, a1;
                if (kc == 8 && quad == 3) {            // k=280..287: weight-zero,
                    a0 = (s16x8){0,0,0,0,0,0,0,0};     // would over-read xbf
                    a1 = a0;
                } else {
                    a0 = cat8(*(const s16x4*)(xbfw + ab0 + kc * 32),
                              *(const s16x4*)(xbfw + ab0 + kc * 32 + 4));
                    a1 = cat8(*(const s16x4*)(xbfw + ab1 + kc * 32),
                              *(const s16x4*)(xbfw + ab1 + kc * 32 + 4));
                }
#pragma unroll
                for (int q = 0; q < 6; ++q) {
                    int nt = g * 6 + q;
                    s16x8 bw = *(const s16x8*)(wb + (nt * 9 + kc) * 512);
                    acc1[q][0] = __builtin_amdgcn_mfma_f32_16x16x32_bf16(a0, bw, acc1[q][0], 0, 0, 0);
                    acc1[q][1] = __builtin_amdgcn_mfma_f32_16x16x32_bf16(a1, bw, acc1[q][1], 0, 0, 0);
                }
            }
#pragma unroll
            for (int q = 0; q < 6; ++q) {
                int n = (g * 6 + q) * 16 + lm;
                if (n < 190) {
                    int ox = n / 10, o = n - ox * 10;
                    float bias = b1[o];
#pragma unroll
                    for (int mt = 0; mt < 2; ++mt) {
#pragma unroll
                        for (int r = 0; r < 4; ++r) {
                            int oy = mt * 16 + quad * 4 + r;
                            if (oy < 19)
                                h1w[oy * ROW1 + ox * 12 + o] =
                                    f2bf(fmaxf(acc1[q][mt][r] + bias, 0.f));
                        }
                    }
                }
            }
        }
    }
    // no barrier: own region, per-wave LDS order.

    // ---- phase 3 (per-wave): conv2 MFMA  M=112(100), N=32(20), K=1280(1000)
    int abase[7];
#pragma unroll
    for (int mt = 0; mt < 7; ++mt) {
        int m = mt * 16 + lm; if (m > 99) m = 99;
        int y = m / 10, xx = m - 10 * y;
        abase[mt] = y * ROW1 + xx * 12 + quad * 8;
    }
    f32x4 acc[7][2] = {};
    {
        const unsigned short* wptr = wbuf2 + lane * 8;
        s16x8 wc0 = *(const s16x8*)(wptr);
        s16x8 wc1 = *(const s16x8*)(wptr + 512);
#pragma unroll
        for (int it = 0; it < 40; ++it) {
            s16x8 wn0 = *(const s16x8*)(wptr + (it + 1) * 1024);   // tail->conv3 region
            s16x8 wn1 = *(const s16x8*)(wptr + (it + 1) * 1024 + 512);
            const unsigned short* sb = h1w + (it >> 2) * ROW1 + (it & 3) * 32;
            s16x8 af[7];
#pragma unroll
            for (int mt = 0; mt < 7; ++mt)
                af[mt] = cat8(*(const s16x4*)(sb + abase[mt]),
                              *(const s16x4*)(sb + abase[mt] + 4));
            __builtin_amdgcn_s_setprio(1);
#pragma unroll
            for (int mt = 0; mt < 7; ++mt) {
                acc[mt][0] = __builtin_amdgcn_mfma_f32_16x16x32_bf16(af[mt], wc0, acc[mt][0], 0, 0, 0);
                acc[mt][1] = __builtin_amdgcn_mfma_f32_16x16x32_bf16(af[mt], wc1, acc[mt][1], 0, 0, 0);
            }
            __builtin_amdgcn_s_setprio(0);
            wc0 = wn0; wc1 = wn1;
        }
    }
    // no barrier: h2 overlays OWN h1 region; per-wave in-order LDS.

    // ---- phase 4 (per-wave): scatter conv2 -> h2w ([x*20+c], ROW2=248) ----
    // h2 pads [200,248) per row read finite old-h1 data under zero weights.
    unsigned short* h2w = h1w;
#pragma unroll
    for (int mt = 0; mt < 7; ++mt) {
#pragma unroll
        for (int nt = 0; nt < 2; ++nt) {
            int o = nt * 16 + lm;
            if (o < 20) {
                float bias = b2[o];
#pragma unroll
                for (int r = 0; r < 4; ++r) {
                    int pos = mt * 16 + quad * 4 + r;
                    if (pos < 100) {
                        int y2 = pos / 10, x2 = pos - 10 * y2;
                        h2w[y2 * ROW2 + x2 * 20 + o] =
                            f2bf(fmaxf(acc[mt][nt][r] + bias, 0.f));
                    }
                }
            }
        }
    }

    // ---- phase 5 (per-wave): conv3 MFMA  M=48(36), N=32(20), K=640(500) ---
    int abase3[3];
#pragma unroll
    for (int mt = 0; mt < 3; ++mt) {
        int m = mt * 16 + lm; if (m > 35) m = 35;
        int oy = m / 6, ox = m - 6 * oy;
        abase3[mt] = oy * ROW2 + ox * 20 + quad * 8;
    }
    f32x4 acc3[3][2] = {};
    {
        const unsigned short* wptr = wbuf3 + lane * 8;
        s16x8 wc0 = *(const s16x8*)(wptr);
        s16x8 wc1 = *(const s16x8*)(wptr + 512);
#pragma unroll
        for (int it = 0; it < 20; ++it) {
            s16x8 wn0 = *(const s16x8*)(wptr + (it + 1) * 1024);   // tail -> wband
            s16x8 wn1 = *(const s16x8*)(wptr + (it + 1) * 1024 + 512);
            const unsigned short* sb = h2w + (it >> 2) * ROW2 + (it & 3) * 32;
            s16x8 af[3];
#pragma unroll
            for (int mt = 0; mt < 3; ++mt)
                af[mt] = cat8(*(const s16x4*)(sb + abase3[mt]),
                              *(const s16x4*)(sb + abase3[mt] + 4));
            __builtin_amdgcn_s_setprio(1);
#pragma unroll
            for (int mt = 0; mt < 3; ++mt) {
                acc3[mt][0] = __builtin_amdgcn_mfma_f32_16x16x32_bf16(af[mt], wc0, acc3[mt][0], 0, 0, 0);
                acc3[mt][1] = __builtin_amdgcn_mfma_f32_16x16x32_bf16(af[mt], wc1, acc3[mt][1], 0, 0, 0);
            }
            __builtin_amdgcn_s_setprio(0);
            wc0 = wn0; wc1 = wn1;
        }
    }

    // ---- phase 6 (per-wave): conv3 epilogue -> h3w[o*36+pos] (fp32, relu) -
    float* h3w = (float*)h1w;                          // overlays own region
#pragma unroll
    for (int mt = 0; mt < 3; ++mt) {
#pragma unroll
        for (int nt = 0; nt < 2; ++nt) {
            int o = nt * 16 + lm;
            if (o < 20) {
                float b3v = b3[o];
#pragma unroll
                for (int r = 0; r < 4; ++r) {
                    int pos = mt * 16 + quad * 4 + r;
                    if (pos < 36)
                        h3w[o * 36 + pos] = fmaxf(acc3[mt][nt][r] + b3v, 0.f);
                }
            }
        }
    }

    // ---- phase 7 (per-wave): fc — coalesced global wf; wave reduce --------
    float part[10];
#pragma unroll
    for (int n = 0; n < 10; ++n) part[n] = 0.f;
#pragma unroll 2
    for (int s = 0; s < 11; ++s) {                     // k = 0..703, no guard
        int k = s * 64 + lane;
        float v = h3w[k];
#pragma unroll
        for (int n = 0; n < 10; ++n)
            part[n] = fmaf(v, wf[n * 720 + k], part[n]);
    }
    {                                                  // tail k = 704..719
        int k = 704 + lane;
        if (lane < 16) {
            float v = h3w[k];
#pragma unroll
            for (int n = 0; n < 10; ++n)
                part[n] = fmaf(v, wf[n * 720 + k], part[n]);
        }
    }
#pragma unroll
    for (int n = 0; n < 10; ++n) {
#pragma unroll
        for (int off = 32; off >= 1; off >>= 1)
            part[n] += __shfl_xor(part[n], off, 64);
    }
    if (lane == 0) {
        float* dst = out + (size_t)img * 10;
#pragma unroll
        for (int n = 0; n < 10; ++n) dst[n] = part[n] + bf[n];
    }
}

extern "C" void kernel_launch(void* const* d_in, const int* in_sizes, int n_in,
                              void* d_out, int out_size, void* d_ws, size_t ws_size,
                              hipStream_t stream) {
    (void)n_in; (void)out_size; (void)ws_size;
    const float* x  = (const float*)d_in[0];
    const float* w1 = (const float*)d_in[1];
    const float* b1 = (const float*)d_in[2];
    const float* w2 = (const float*)d_in[3];
    const float* b2 = (const float*)d_in[4];
    const float* w3 = (const float*)d_in[5];
    const float* b3 = (const float*)d_in[6];
    const float* wf = (const float*)d_in[7];
    const float* bf = (const float*)d_in[8];
    float* out = (float*)d_out;

    const int B = in_sizes[0] / 784;                   // 4096

    unsigned short* wbuf = (unsigned short*)d_ws;      // 116736 bf16 = 228 KB

    wprep_k<<<456, 256, 0, stream>>>(w1, w2, w3, wbuf);
    fused_k<<<B / 2, 128, 0, stream>>>(x, b1, wbuf, wbuf + 40960, wbuf + 61440,
                                       b2, b3, wf, bf, out);
}